// Round 3
// baseline (120.715 us; speedup 1.0000x reference)
//
#include <hip/hip_runtime.h>
#include <stdint.h>

// TargetTokenEncoder: histogram-stats -> MLP(14->256 GELU ->256) fused.
// R3: 512-thread blocks (8 waves, 100% occupancy at 4 blocks/CU) and
// swapped MFMA operands (A=weights i=n, B=stats/h j=m) so C/D reg-groups
// hold 4 consecutive features -> ds_write_b64 h-stores and dwordx4 out-stores.

#define SSUP 128
#define DD   256

typedef __attribute__((ext_vector_type(8)))  short bf16x8;   // 8 bf16 = 4 VGPRs
typedef __attribute__((ext_vector_type(16))) float f32x16;   // C/D for 32x32 MFMA

__device__ __forceinline__ unsigned f2bf_u(float f) {
    union { float f; unsigned u; } v; v.f = f;
    return (v.u + 0x7FFFu + ((v.u >> 16) & 1u)) >> 16;   // RNE, no NaNs here
}
__device__ __forceinline__ unsigned pk2(float a, float b) {
    return f2bf_u(a) | (f2bf_u(b) << 16);
}

// tanh-form GELU; |dev from exact erf-GELU| < 0.003 << tolerance.
__device__ __forceinline__ float gelu_f(float x) {
    float z = 0.7978845608028654f * x * (1.0f + 0.044715f * x * x);
    float e = __expf(-2.0f * z);
    float th = 2.0f / (1.0f + e) - 1.0f;
    return 0.5f * x * (1.0f + th);
}

// Fragment-major weights (A-operand now: i = n = 32nt + (l&31), k = (l>>5)*8+j):
//   w2f[((s*8 + nt)*64 + l)*8 + j] = bf16(w2[(s*16 + (l>>5)*8 + j)*256 + n])
//   w1f[(nt*64 + l)*8 + j]         = bf16(w1[((l>>5)*8+j)*256 + n]), pad k>=14
__global__ void prep_kernel(const float* __restrict__ w1,
                            const float* __restrict__ w2,
                            unsigned short* __restrict__ w1f,
                            unsigned short* __restrict__ w2f) {
    int tid = blockIdx.x * 256 + threadIdx.x;
    if (tid < 8192) {                       // w2f: one thread per (s,nt,lane)
        int l  = tid & 63;
        int nt = (tid >> 6) & 7;
        int s  = tid >> 9;
        int n  = nt * 32 + (l & 31);
        int k0 = s * 16 + (l >> 5) * 8;
        unsigned pk[4];
        #pragma unroll
        for (int h = 0; h < 4; ++h)
            pk[h] = pk2(w2[(size_t)(k0 + 2*h) * DD + n],
                        w2[(size_t)(k0 + 2*h + 1) * DD + n]);
        *(uint4*)&w2f[(size_t)tid * 8] = make_uint4(pk[0], pk[1], pk[2], pk[3]);
    } else if (tid < 8704) {                // w1f
        int idx = tid - 8192;
        int l   = idx & 63;
        int nt  = idx >> 6;
        int n   = nt * 32 + (l & 31);
        int kk0 = (l >> 5) * 8;
        unsigned pk[4];
        #pragma unroll
        for (int h = 0; h < 4; ++h) {
            int ka = kk0 + 2*h, kb = kk0 + 2*h + 1;
            float fa = (ka < 14) ? w1[(size_t)ka * DD + n] : 0.0f;
            float fb = (kb < 14) ? w1[(size_t)kb * DD + n] : 0.0f;
            pk[h] = pk2(fa, fb);
        }
        *(uint4*)&w1f[(size_t)idx * 8] = make_uint4(pk[0], pk[1], pk[2], pk[3]);
    }
}

__global__ __launch_bounds__(512, 8)
void encoder_kernel(const int* __restrict__ y,
                    const float* __restrict__ b1,
                    const float* __restrict__ b2,
                    const unsigned short* __restrict__ w1f,
                    const unsigned short* __restrict__ w2f,
                    float* __restrict__ out) {
    __shared__ __align__(16) unsigned short stats_a[64][16];   // 2 KB
    __shared__ __align__(16) unsigned short h_lds[64][264];    // 33 KB (16B-aligned rows)

    const int tid = threadIdx.x;
    const int r0 = blockIdx.x * 64;

    // ---------------- Phase 1: histogram + stats ----------------
    // 8 threads/row, 16 labels each (4x int4, q-interleaved 64B runs);
    // 10 counters packed 6b in u64 (per-thread max 16 < 64).
    const int rl = tid >> 3;     // local row 0..63
    const int q  = tid & 7;
    const int4* yp = (const int4*)(y + (size_t)(r0 + rl) * SSUP);
    unsigned long long pkc = 0ull;
    #pragma unroll
    for (int i = 0; i < 4; ++i) {
        int4 v = yp[i * 8 + q];
        pkc += 1ull << (6 * v.x);
        pkc += 1ull << (6 * v.y);
        pkc += 1ull << (6 * v.z);
        pkc += 1ull << (6 * v.w);
    }
    float p[10]; float ent = 0.f, pmax = 0.f, nnz = 0.f;
    #pragma unroll
    for (int c = 0; c < 10; ++c) {
        int cc = (int)((pkc >> (6 * c)) & 63ull);
        cc += __shfl_xor(cc, 1);     // row's 8 threads are adjacent lanes
        cc += __shfl_xor(cc, 2);
        cc += __shfl_xor(cc, 4);
        float pc = (float)cc * 0.0078125f;        // total is always 128
        p[c] = pc;
        nnz += (cc > 0) ? 1.0f : 0.0f;
        ent -= pc * __logf(pc + 1e-6f);
        pmax = fmaxf(pmax, pc);
    }
    if (q < 2) {
        unsigned a0, a1, a2, a3;
        if (q == 0) { a0 = pk2(p[0], p[1]); a1 = pk2(p[2], p[3]);
                      a2 = pk2(p[4], p[5]); a3 = pk2(p[6], p[7]); }
        else        { a0 = pk2(p[8], p[9]); a1 = pk2(nnz, ent);
                      a2 = pk2(128.0f, pmax); a3 = 0u; }
        *(uint4*)&stats_a[rl][q * 8] = make_uint4(a0, a1, a2, a3);
    }
    __syncthreads();

    const int lane = tid & 63;
    const int wid  = tid >> 6;   // 0..7
    const int wm   = wid & 1;    // M half: rows 32*wm..+31
    const int wn   = wid >> 1;   // N quarter: cols 64*wn..+63 (nt = 2wn, 2wn+1)
    const int l31  = lane & 31;
    const int lh   = lane >> 5;
    const int m    = 32 * wm + l31;   // this lane's batch row (D col)

    // ---------------- Phase 2: GEMM1 (hT tiles) + GELU -> h_lds ----------------
    // D1[i=n][j=m]: A = w1f (i=n), B = stats (j=m). Lane: col j=m fixed,
    // rows n = 32nt + (r&3)+8*(r>>2)+4*lh -> runs of 4 consecutive features.
    bf16x8 sfrag = *(const bf16x8*)&stats_a[m][lh * 8];
    #pragma unroll
    for (int t = 0; t < 2; ++t) {
        const int nt = wn * 2 + t;
        bf16x8 wfrag = *(const bf16x8*)&w1f[(size_t)(nt * 64 + lane) * 8];
        f32x16 c;
        #pragma unroll
        for (int g = 0; g < 4; ++g) {
            float4 bv = *(const float4*)&b1[nt * 32 + 8 * g + 4 * lh];
            c[4*g+0] = bv.x; c[4*g+1] = bv.y; c[4*g+2] = bv.z; c[4*g+3] = bv.w;
        }
        c = __builtin_amdgcn_mfma_f32_32x32x16_bf16(wfrag, sfrag, c, 0, 0, 0);
        #pragma unroll
        for (int g = 0; g < 4; ++g) {
            unsigned u0 = pk2(gelu_f(c[4*g+0]), gelu_f(c[4*g+1]));
            unsigned u1 = pk2(gelu_f(c[4*g+2]), gelu_f(c[4*g+3]));
            *(uint2*)&h_lds[m][nt * 32 + 8 * g + 4 * lh] = make_uint2(u0, u1);
        }
    }
    __syncthreads();

    // ---------------- Phase 3: GEMM2 (outT tiles) -> out ----------------
    f32x16 acc[2];
    #pragma unroll
    for (int u = 0; u < 2; ++u) {
        const int nt = wn * 2 + u;
        #pragma unroll
        for (int g = 0; g < 4; ++g) {
            float4 bv = *(const float4*)&b2[nt * 32 + 8 * g + 4 * lh];
            acc[u][4*g+0] = bv.x; acc[u][4*g+1] = bv.y;
            acc[u][4*g+2] = bv.z; acc[u][4*g+3] = bv.w;
        }
    }
    #pragma unroll
    for (int s = 0; s < 16; ++s) {
        bf16x8 hfrag = *(const bf16x8*)&h_lds[m][s * 16 + lh * 8];
        #pragma unroll
        for (int u = 0; u < 2; ++u) {
            const int nt = wn * 2 + u;
            bf16x8 wfrag = *(const bf16x8*)
                &w2f[(size_t)((s * 8 + nt) * 64 + lane) * 8];
            acc[u] = __builtin_amdgcn_mfma_f32_32x32x16_bf16(wfrag, hfrag, acc[u], 0, 0, 0);
        }
    }
    #pragma unroll
    for (int u = 0; u < 2; ++u) {
        const int nt = wn * 2 + u;
        #pragma unroll
        for (int g = 0; g < 4; ++g) {
            float4 o;
            o.x = acc[u][4*g+0]; o.y = acc[u][4*g+1];
            o.z = acc[u][4*g+2]; o.w = acc[u][4*g+3];
            *(float4*)&out[(size_t)(r0 + m) * DD + nt * 32 + 8 * g + 4 * lh] = o;
        }
    }
}

extern "C" void kernel_launch(void* const* d_in, const int* in_sizes, int n_in,
                              void* d_out, int out_size, void* d_ws, size_t ws_size,
                              hipStream_t stream) {
    const int*   y  = (const int*)d_in[0];
    const float* w1 = (const float*)d_in[1];
    const float* b1 = (const float*)d_in[2];
    const float* w2 = (const float*)d_in[3];
    const float* b2 = (const float*)d_in[4];
    float* out = (float*)d_out;

    unsigned short* w2f = (unsigned short*)d_ws;        // 65536 shorts (128 KB)
    unsigned short* w1f = w2f + 65536;                  // 4096 shorts (8 KB)

    prep_kernel<<<34, 256, 0, stream>>>(w1, w2, w1f, w2f);

    const int nrows = in_sizes[0] / SSUP;               // 65536
    encoder_kernel<<<nrows / 64, 512, 0, stream>>>(y, b1, b2, w1f, w2f, out);
}